// Round 2
// baseline (242.771 us; speedup 1.0000x reference)
//
#include <hip/hip_runtime.h>

// Stride-2 3x3 conv as implicit GEMM, f16 MFMA 32x32x16.
// Block = 128 co x 256 n (8 oh rows x 32 ow), 4 waves, wave tile 64co x 128n.
// Double-buffered LDS, prefetch distance 1, global_load_lds for weights,
// register-staged fp32->f16 x conversion, conflict-free LDS layouts.

#define CIN  256
#define H_   64
#define W_   64
#define OH   32
#define OW   32
#define HW   4096

typedef _Float16 f16;
typedef _Float16 half8 __attribute__((ext_vector_type(8)));
typedef float    floatx16 __attribute__((ext_vector_type(16)));

// ws chunk: [khw 9][h 2][co 128][8]   = 18432 f16 = 36864 B
// xs chunk: [r 17][p 2][h 2][idx 33][8] = 17952 f16 = 35904 B
#define WS_CH 18432
#define XS_CH 17952

typedef const __attribute__((address_space(1))) void g_void;
typedef __attribute__((address_space(3))) void l_void;

__global__ __launch_bounds__(256) void repack_w_kernel(const float* __restrict__ w,
                                                       f16* __restrict__ rp) {
  int o = blockIdx.x * 256 + threadIdx.x;   // 589824 total, exact
  int ci8  = o & 7;
  int t1   = o >> 3;
  int co_l = t1 & 127;
  int t2   = t1 >> 7;
  int h    = t2 & 1;
  int t3   = t2 >> 1;
  int khw  = t3 % 9;
  int t4   = t3 / 9;
  int cc   = t4 & 15;
  int co_t = t4 >> 4;
  int ci = cc * 16 + h * 8 + ci8;
  int co = co_t * 128 + co_l;
  rp[o] = (f16)w[(co * CIN + ci) * 9 + khw];
}

__global__ __launch_bounds__(256, 1) void conv_mfma_kernel(
    const float* __restrict__ x, const f16* __restrict__ rp,
    float* __restrict__ out) {
  extern __shared__ f16 smem[];
  f16* wsb = smem;               // 2 * WS_CH
  f16* xsb = smem + 2 * WS_CH;   // 2 * XS_CH

  const int t    = threadIdx.x;
  const int lane = t & 63;
  const int wave = t >> 6;
  const int h    = lane >> 5;    // k-half
  const int ml   = lane & 31;
  const int wm   = wave >> 1;    // co half (64)
  const int wn   = wave & 1;     // n half (4 oh rows)

  // blk = co_t*128 + b*4 + ohg  -> co_t pairs share XCD (delta 128 % 8 == 0)
  const int blk  = blockIdx.x;
  const int co_t = blk >> 7;
  const int rem  = blk & 127;
  const int b    = rem >> 2;
  const int ohg  = rem & 3;
  const int oh0  = ohg * 8;
  const int ih0  = oh0 * 2 - 1;

  const float* xb  = x  + (size_t)b * CIN * HW;
  const f16*   rpb = rp + (size_t)co_t * (16 * WS_CH);

  // zero the left-pad column (odd plane idx 0), both halves, both buffers
  if (t < 68) {
    int r = t >> 2, hh = t & 1, bufsel = (t >> 1) & 1;
    half8 z = {};
    *(half8*)&xsb[bufsel * XS_CH + (((r * 2 + 1) * 2 + hh) * 33 + 0) * 8] = z;
  }

  const int iw  = t & 63;
  const int p   = iw & 1;
  const int idx = (iw + p) >> 1;

  floatx16 acc[2][4];
#pragma unroll
  for (int mi = 0; mi < 2; ++mi)
#pragma unroll
    for (int nj = 0; nj < 4; ++nj)
#pragma unroll
      for (int i = 0; i < 16; ++i) acc[mi][nj][i] = 0.f;

  float xr[5][16];   // x staging registers (wave 0 uses all 5 rows)

  auto load_x = [&](int c) {
#pragma unroll
    for (int k = 0; k < 5; ++k) {
      if (k < 4 || wave == 0) {
        int r  = wave + 4 * k;          // 0..16
        int ih = ih0 + r;
        const float* xp = xb + (size_t)(c * 16) * HW + (size_t)ih * W_ + iw;
        if (ih >= 0) {
#pragma unroll
          for (int j = 0; j < 16; ++j) xr[k][j] = xp[(size_t)j * HW];
        } else {
#pragma unroll
          for (int j = 0; j < 16; ++j) xr[k][j] = 0.f;
        }
      }
    }
  };

  auto write_x = [&](int buf) {
    f16* xd = xsb + buf * XS_CH;
#pragma unroll
    for (int k = 0; k < 5; ++k) {
      if (k < 4 || wave == 0) {
        int r = wave + 4 * k;
        half8 v0, v1;
#pragma unroll
        for (int j = 0; j < 8; ++j) {
          v0[j] = (f16)xr[k][j];
          v1[j] = (f16)xr[k][j + 8];
        }
        *(half8*)&xd[(((r * 2 + p) * 2 + 0) * 33 + idx) * 8] = v0;
        *(half8*)&xd[(((r * 2 + p) * 2 + 1) * 33 + idx) * 8] = v1;
      }
    }
  };

  auto dma_w = [&](int c, int buf) {
    const char* src = (const char*)rpb + (size_t)c * 36864 + wave * 9216 + lane * 16;
    char* dst = (char*)(wsb + buf * WS_CH) + wave * 9216 + lane * 16;
#pragma unroll
    for (int i = 0; i < 9; ++i)
      __builtin_amdgcn_global_load_lds((g_void*)(src + i * 1024),
                                       (l_void*)(dst + i * 1024), 16, 0, 0);
  };

  auto compute = [&](int buf) {
    const f16* wsc = wsb + buf * WS_CH;
    const f16* xsc = xsb + buf * XS_CH;
#pragma unroll
    for (int kh = 0; kh < 3; ++kh) {
#pragma unroll
      for (int kw = 0; kw < 3; ++kw) {
        const int khw = kh * 3 + kw;
        half8 a0 = *(const half8*)&wsc[((khw * 2 + h) * 128 + wm * 64 + ml) * 8];
        half8 a1 = *(const half8*)&wsc[((khw * 2 + h) * 128 + wm * 64 + 32 + ml) * 8];
        const int pp = (kw & 1) ^ 1;     // kw=1 -> even plane
        const int ix = ml + (kw >> 1);
#pragma unroll
        for (int nj = 0; nj < 4; ++nj) {
          const int r = 2 * (wn * 4 + nj) + kh;
          half8 bf = *(const half8*)&xsc[(((r * 2 + pp) * 2 + h) * 33 + ix) * 8];
          acc[0][nj] = __builtin_amdgcn_mfma_f32_32x32x16_f16(a0, bf, acc[0][nj], 0, 0, 0);
          acc[1][nj] = __builtin_amdgcn_mfma_f32_32x32x16_f16(a1, bf, acc[1][nj], 0, 0, 0);
        }
      }
    }
  };

  // prologue: stage chunk 0 into buffer 0
  load_x(0);
  dma_w(0, 0);
  write_x(0);
  __syncthreads();

  for (int cc = 0; cc < 16; ++cc) {
    const int nb = (cc + 1) & 1;
    if (cc < 15) {
      load_x(cc + 1);      // global -> regs (latency hidden by compute)
      dma_w(cc + 1, nb);   // global -> LDS DMA
    }
    compute(cc & 1);
    if (cc < 15) write_x(nb);  // cvt + ds_write after the MFMA stream
    __syncthreads();           // structural drain waits on loads issued ~2300 cyc ago
  }

  // epilogue: C/D col = lane&31 (=ow), row = (reg&3) + 8*(reg>>2) + 4*(lane>>5)
  float* ob = out + ((size_t)b * 256 + co_t * 128 + wm * 64) * (OH * OW);
  const int rb4 = h * 4;
#pragma unroll
  for (int mi = 0; mi < 2; ++mi) {
#pragma unroll
    for (int nj = 0; nj < 4; ++nj) {
      const int oh = oh0 + wn * 4 + nj;
#pragma unroll
      for (int r = 0; r < 16; ++r) {
        const int row = mi * 32 + (r & 3) + 8 * (r >> 2) + rb4;
        ob[(size_t)row * (OH * OW) + oh * OW + ml] = acc[mi][nj][r];
      }
    }
  }
}

extern "C" void kernel_launch(void* const* d_in, const int* in_sizes, int n_in,
                              void* d_out, int out_size, void* d_ws, size_t ws_size,
                              hipStream_t stream) {
  const float* x = (const float*)d_in[0];   // [32][256][64][64] fp32
  const float* w = (const float*)d_in[1];   // [256][256][3][3]  fp32
  float* out = (float*)d_out;               // [32][256][32][32] fp32
  f16* rp = (f16*)d_ws;                     // 1.18 MB repacked f16 weights

  hipFuncSetAttribute((const void*)conv_mfma_kernel,
                      hipFuncAttributeMaxDynamicSharedMemorySize,
                      2 * (WS_CH + XS_CH) * (int)sizeof(f16));

  repack_w_kernel<<<2304, 256, 0, stream>>>(w, rp);
  conv_mfma_kernel<<<256, 256, 2 * (WS_CH + XS_CH) * sizeof(f16), stream>>>(x, rp, out);
}